// Round 8
// baseline (658.849 us; speedup 1.0000x reference)
//
#include <hip/hip_runtime.h>
#include <hip/hip_bf16.h>

// Problem: S=2048, D_MODEL=2048, H=16, HD=128
// out = softmax1((q@Wq^T)(k@Wk^T)^T / sqrt(HD)) @ (v@Wv^T) * scalars @ Wo^T
//
// Round 14:
//  - POST-MORTEM r13: launch_bounds(512,4) capped VGPR at 64 -> scratch
//    spills (WRITE_SIZE 16->24MB, FETCH +4MB), attn 185us. Structural fail;
//    setprio/defer-max never isolated. NEVER set min-waves on this kernel.
//  - attn_mfma v5 = r11 EXACT structure (136.6us verified: QBLK=64, 256thr,
//    VT in LDS, T14 reg prefetch, 2 barriers/tile, head-local XCD swizzle,
//    launch_bounds(256) only, 112 VGPR no-spill) + ONLY two proven adds:
//    T5 setprio around MFMA clusters (+4-7% m191) and T13 defer-max (+5%;
//    absmax bit-identical in r12/r13 -> numerically safe).
//  - gemm_nt3/conv2: unchanged from r10 (verified).

#define S_LEN 2048
#define DMODEL 2048
#define NHEAD 16
#define HEADD 128

typedef __bf16 bf16x8 __attribute__((ext_vector_type(8)));
typedef __bf16 bf16x4 __attribute__((ext_vector_type(4)));
typedef float f32x4 __attribute__((ext_vector_type(4)));

__device__ inline void async_copy16(const __bf16* g, __bf16* l) {
    __builtin_amdgcn_global_load_lds(
        (const __attribute__((address_space(1))) unsigned int*)g,
        (__attribute__((address_space(3))) unsigned int*)l, 16, 0, 0);
}

// ---- fp32 -> hi/lo bf16 split conversion, up to 2 matrices per launch ----
__global__ __launch_bounds__(256) void conv2(const float* __restrict__ s0,
                                             __hip_bfloat16* __restrict__ h0,
                                             __hip_bfloat16* __restrict__ l0,
                                             float sc0,
                                             const float* __restrict__ s1,
                                             __hip_bfloat16* __restrict__ h1,
                                             __hip_bfloat16* __restrict__ l1,
                                             float sc1) {
    const float* s = blockIdx.y ? s1 : s0;
    __hip_bfloat16* ph = blockIdx.y ? h1 : h0;
    __hip_bfloat16* pl = blockIdx.y ? l1 : l0;
    const float sc = blockIdx.y ? sc1 : sc0;
    size_t i4 = (size_t)blockIdx.x * 256 + threadIdx.x;  // float4 index
    float4 v = *(const float4*)&s[i4 * 4];
    float x0 = v.x * sc, x1 = v.y * sc, x2 = v.z * sc, x3 = v.w * sc;
    bf16x4 hv, lv;
    __bf16 a0 = (__bf16)x0, a1 = (__bf16)x1, a2 = (__bf16)x2, a3 = (__bf16)x3;
    hv[0] = a0; hv[1] = a1; hv[2] = a2; hv[3] = a3;
    lv[0] = (__bf16)(x0 - (float)a0); lv[1] = (__bf16)(x1 - (float)a1);
    lv[2] = (__bf16)(x2 - (float)a2); lv[3] = (__bf16)(x3 - (float)a3);
    *(bf16x4*)&ph[i4 * 4] = hv;
    *(bf16x4*)&pl[i4 * 4] = lv;
}

struct GArgs {
    const __bf16 *Ah, *Al, *Bh, *Bl;
    float* Cf;
    __bf16 *Ch, *Cl;
};

// ---- C = A @ B^T, pre-split hi/lo planes. Tile 128(M) x 128(N), BK=32.
// 256 threads = 4 waves in 2x2 grid; each wave owns a 64x64 sub-tile.
// Double-buffered LDS (64KB, 2 blocks/CU); one barrier per K-step.
// OUTMODE: 0 = fp32, 1 = bf16, 2 = hi/lo bf16 planes. blockIdx.z picks g0/g1.
template <int OUTMODE>
__global__ __launch_bounds__(256, 2) void gemm_nt3(GArgs g0, GArgs g1) {
    constexpr int K = DMODEL, N = DMODEL;
    const GArgs g = blockIdx.z ? g1 : g0;
    __shared__ __bf16 sAh[2][128 * 32], sAl[2][128 * 32];
    __shared__ __bf16 sBh[2][128 * 32], sBl[2][128 * 32];

    const int tid = threadIdx.x;   // 0..255
    const int lane = tid & 63;
    const int wave = tid >> 6;     // 0..3
    const int wr = wave >> 1;      // wave-row (2)
    const int wc = wave & 1;       // wave-col (2)
    const int qr = lane & 15;
    const int quad = lane >> 4;

    // XCD-bijective swizzle over the 16x16 2D grid (nwg=256, %8==0):
    // consecutive swz ids share the same XCD and the same A-panel row block.
    const int flat = blockIdx.y * gridDim.x + blockIdx.x;
    const int swz = (flat & 7) * 32 + (flat >> 3);
    const size_t row0 = (size_t)(swz >> 4) * 128;
    const size_t col0 = (size_t)(swz & 15) * 128;

    // staging: chunk (c*256+tid) -> LDS row = c*64 + (tid>>2), slot = tid&3;
    // slot holds global k-chunk (slot ^ (row&3)); read undoes with quad^(qr&3).
    const int srow = tid >> 2;
    const int k8 = (((tid & 3) ^ ((tid >> 2) & 3)) * 8);
    const __bf16* gAh = g.Ah + (row0 + srow) * K + k8;
    const __bf16* gAl = g.Al + (row0 + srow) * K + k8;
    const __bf16* gBh = g.Bh + (col0 + srow) * K + k8;
    const __bf16* gBl = g.Bl + (col0 + srow) * K + k8;

    f32x4 acc[4][4] = {};

    // issue 8 global_load_lds (32KB) for K-tile at column k0 into buffer b
    auto stage = [&](int b, int k0) {
#pragma unroll
        for (int c = 0; c < 2; ++c) {
            async_copy16(gAh + k0 + (size_t)c * 64 * K, &sAh[b][c * 2048 + tid * 8]);
            async_copy16(gAl + k0 + (size_t)c * 64 * K, &sAl[b][c * 2048 + tid * 8]);
            async_copy16(gBh + k0 + (size_t)c * 64 * K, &sBh[b][c * 2048 + tid * 8]);
            async_copy16(gBl + k0 + (size_t)c * 64 * K, &sBl[b][c * 2048 + tid * 8]);
        }
    };

    stage(0, 0);
    __syncthreads();  // prologue drain: buf0 ready

    const int aslot = (quad ^ (qr & 3)) * 8;
    int cur = 0;
    for (int k0 = 0; k0 < K; k0 += 32) {
        if (k0 + 32 < K) stage(cur ^ 1, k0 + 32);  // prefetch next tile

        bf16x8 a_h[4], a_l[4], b_h[4], b_l[4];
#pragma unroll
        for (int i = 0; i < 4; ++i) {
            a_h[i] = *(const bf16x8*)&sAh[cur][(wr * 64 + i * 16 + qr) * 32 + aslot];
            a_l[i] = *(const bf16x8*)&sAl[cur][(wr * 64 + i * 16 + qr) * 32 + aslot];
        }
#pragma unroll
        for (int j = 0; j < 4; ++j) {
            b_h[j] = *(const bf16x8*)&sBh[cur][(wc * 64 + j * 16 + qr) * 32 + aslot];
            b_l[j] = *(const bf16x8*)&sBl[cur][(wc * 64 + j * 16 + qr) * 32 + aslot];
        }
#pragma unroll
        for (int i = 0; i < 4; ++i)
#pragma unroll
            for (int j = 0; j < 4; ++j) {
                acc[i][j] = __builtin_amdgcn_mfma_f32_16x16x32_bf16(a_h[i], b_h[j], acc[i][j], 0, 0, 0);
                acc[i][j] = __builtin_amdgcn_mfma_f32_16x16x32_bf16(a_h[i], b_l[j], acc[i][j], 0, 0, 0);
                acc[i][j] = __builtin_amdgcn_mfma_f32_16x16x32_bf16(a_l[i], b_h[j], acc[i][j], 0, 0, 0);
            }
        __syncthreads();  // prefetch landed (vmcnt) + all reads of buf[cur] done
        cur ^= 1;
    }

    // epilogue: C/D layout col=lane&15, row=quad*4+reg
#pragma unroll
    for (int i = 0; i < 4; ++i)
#pragma unroll
        for (int j = 0; j < 4; ++j)
#pragma unroll
            for (int r = 0; r < 4; ++r) {
                size_t idx = (row0 + wr * 64 + i * 16 + quad * 4 + r) * N +
                             col0 + wc * 64 + j * 16 + qr;
                float x = acc[i][j][r];
                if (OUTMODE == 0) {
                    g.Cf[idx] = x;
                } else if (OUTMODE == 1) {
                    g.Ch[idx] = (__bf16)x;
                } else {
                    __bf16 hv = (__bf16)x;
                    g.Ch[idx] = hv;
                    g.Cl[idx] = (__bf16)(x - (float)hv);
                }
            }
}

// MFMA flash attention. Block = 64 q-rows x 1 head; 4 waves x 16 rows each.
// v5 = r11 structure (VT in LDS, T14 reg prefetch, 2 barriers/tile,
// head-local XCD swizzle, NO launch_bounds cap) + setprio + defer-max.
__global__ __launch_bounds__(256) void attn_mfma(const __bf16* __restrict__ qhi_g,
                                                 const __bf16* __restrict__ qlo_g,
                                                 const __bf16* __restrict__ khi_g,
                                                 const __bf16* __restrict__ klo_g,
                                                 const __bf16* __restrict__ vhT,
                                                 const float* __restrict__ scalars,
                                                 __bf16* __restrict__ ohi_g,
                                                 __bf16* __restrict__ olo_g) {
    // head-locality XCD swizzle: XCD x (= flatb%8 dispatch round-robin) owns
    // heads {2x, 2x+1}; K/V working set per XCD = 2.5MB < 4MB L2. Bijective.
    const int flatb = blockIdx.y * gridDim.x + blockIdx.x;  // 0..511
    const int ib = flatb >> 3;                              // 0..63
    const int h = (flatb & 7) * 2 + (ib >> 5);
    const int q0 = (ib & 31) * 64;

    __shared__ __align__(16) __bf16 Khi[64][136];  // padded: 272B stride
    __shared__ __align__(16) __bf16 Klo[64][136];
    __shared__ __align__(16) __bf16 VT[128][72];   // [head-dim][kpos], 144B stride
    __shared__ __align__(16) __bf16 Ps[64][72];    // [q-row][kpos] (wave-private rows)

    const int tid = threadIdx.x;
    const int lane = tid & 63;
    const int wave = tid >> 6;
    const int qr = lane & 15;
    const int quad = lane >> 4;

    // per-thread staging coordinates (fixed across tiles)
    const int kp0 = tid >> 4;           // K row base (+16 per chunk), 0..15
    const int kc8 = (tid & 15) * 8;     // K col byte-slot
    const int dm0 = tid >> 3;           // V row base (+32 per chunk), 0..31
    const int vc8 = (tid & 7) * 8;      // V col slot
    const __bf16* gK_hi = khi_g + (size_t)kp0 * DMODEL + h * HEADD + kc8;
    const __bf16* gK_lo = klo_g + (size_t)kp0 * DMODEL + h * HEADD + kc8;
    const __bf16* gVT = vhT + (size_t)(h * HEADD + dm0) * S_LEN + vc8;

    bf16x8 qfh[4], qfl[4];
    {
        const __bf16* qrh = qhi_g + (size_t)(q0 + wave * 16 + qr) * DMODEL + h * HEADD;
        const __bf16* qrl = qlo_g + (size_t)(q0 + wave * 16 + qr) * DMODEL + h * HEADD;
#pragma unroll
        for (int kc = 0; kc < 4; ++kc) {
            qfh[kc] = *(const bf16x8*)&qrh[kc * 32 + quad * 8];
            qfl[kc] = *(const bf16x8*)&qrl[kc * 32 + quad * 8];
        }
    }

    // register-staged K/V tile (T14 async split): 12 x 16B per thread
    bf16x8 rKh[4], rKl[4], rV[4];
    auto load_regs = [&](int k0) {
#pragma unroll
        for (int i = 0; i < 4; ++i) {
            size_t go = (size_t)(k0 + i * 16) * DMODEL;
            rKh[i] = *(const bf16x8*)&gK_hi[go];
            rKl[i] = *(const bf16x8*)&gK_lo[go];
            rV[i] = *(const bf16x8*)&gVT[(size_t)(i * 32) * S_LEN + k0];
        }
    };
    auto write_lds = [&]() {
#pragma unroll
        for (int i = 0; i < 4; ++i) {
            *(bf16x8*)&Khi[kp0 + i * 16][kc8] = rKh[i];
            *(bf16x8*)&Klo[kp0 + i * 16][kc8] = rKl[i];
            *(bf16x8*)&VT[dm0 + i * 32][vc8] = rV[i];
        }
    };

    f32x4 oacc[8] = {};
    float m_r[4], l_r[4];
#pragma unroll
    for (int r = 0; r < 4; ++r) { m_r[r] = 0.f; l_r[r] = 1.f; }  // softmax1 init

    load_regs(0);
    for (int k0 = 0; k0 < S_LEN; k0 += 64) {
        write_lds();          // lgkmcnt ordering by compiler
        __syncthreads();      // tile k0 visible to all waves
        if (k0 + 64 < S_LEN) load_regs(k0 + 64);  // flies under compute

        f32x4 S[4] = {};
        __builtin_amdgcn_s_setprio(1);
#pragma unroll
        for (int jt = 0; jt < 4; ++jt) {
#pragma unroll
            for (int kc = 0; kc < 4; ++kc) {
                bf16x8 kh8 = *(const bf16x8*)&Khi[jt * 16 + qr][kc * 32 + quad * 8];
                bf16x8 kl8 = *(const bf16x8*)&Klo[jt * 16 + qr][kc * 32 + quad * 8];
                S[jt] = __builtin_amdgcn_mfma_f32_16x16x32_bf16(qfh[kc], kh8, S[jt], 0, 0, 0);
                S[jt] = __builtin_amdgcn_mfma_f32_16x16x32_bf16(qfh[kc], kl8, S[jt], 0, 0, 0);
                S[jt] = __builtin_amdgcn_mfma_f32_16x16x32_bf16(qfl[kc], kh8, S[jt], 0, 0, 0);
            }
        }
        __builtin_amdgcn_s_setprio(0);

#pragma unroll
        for (int r = 0; r < 4; ++r) {
            float mx = fmaxf(fmaxf(S[0][r], S[1][r]), fmaxf(S[2][r], S[3][r]));
#pragma unroll
            for (int m = 1; m < 16; m <<= 1) mx = fmaxf(mx, __shfl_xor(mx, m, 64));
            // T13 defer-max: keep m_old while tile max growth <= 8 (P <= e^8,
            // bf16-safe; absmax bit-identical with this on in r12/r13)
            int skip = __all(mx - m_r[r] <= 8.0f);
            float m_new = skip ? m_r[r] : fmaxf(m_r[r], mx);
            float sum = 0.f;
            int prow = wave * 16 + quad * 4 + r;
#pragma unroll
            for (int jt = 0; jt < 4; ++jt) {
                float e = __expf(S[jt][r] - m_new);
                sum += e;
                Ps[prow][jt * 16 + qr] = (__bf16)e;
            }
#pragma unroll
            for (int m = 1; m < 16; m <<= 1) sum += __shfl_xor(sum, m, 64);
            if (skip) {
                l_r[r] += sum;
            } else {
                float alpha = __expf(m_r[r] - m_new);
                l_r[r] = l_r[r] * alpha + sum;
                m_r[r] = m_new;
#pragma unroll
                for (int nt = 0; nt < 8; ++nt) oacc[nt][r] *= alpha;
            }
        }
        // NO barrier: Ps rows [wave*16, wave*16+16) are wave-private.

        __builtin_amdgcn_s_setprio(1);
#pragma unroll
        for (int kc = 0; kc < 2; ++kc) {
            bf16x8 pf = *(const bf16x8*)&Ps[wave * 16 + qr][kc * 32 + quad * 8];
#pragma unroll
            for (int nt = 0; nt < 8; ++nt) {
                bf16x8 vf = *(const bf16x8*)&VT[nt * 16 + qr][kc * 32 + quad * 8];
                oacc[nt] = __builtin_amdgcn_mfma_f32_16x16x32_bf16(pf, vf, oacc[nt], 0, 0, 0);
            }
        }
        __builtin_amdgcn_s_setprio(0);
        __syncthreads();  // all waves done reading K/VT before next write_lds
    }

    const float sh = scalars[h];
#pragma unroll
    for (int r = 0; r < 4; ++r) {
        float wm = sh / l_r[r];
        size_t rowoff = (size_t)(q0 + wave * 16 + quad * 4 + r) * DMODEL + h * HEADD;
#pragma unroll
        for (int nt = 0; nt < 8; ++nt) {
            float x = oacc[nt][r] * wm;
            __bf16 hv = (__bf16)x;
            ohi_g[rowoff + nt * 16 + qr] = hv;
            olo_g[rowoff + nt * 16 + qr] = (__bf16)(x - (float)hv);
        }
    }
}

extern "C" void kernel_launch(void* const* d_in, const int* in_sizes, int n_in,
                              void* d_out, int out_size, void* d_ws, size_t ws_size,
                              hipStream_t stream) {
    const float* query   = (const float*)d_in[0];
    const float* key_    = (const float*)d_in[1];
    const float* value   = (const float*)d_in[2];
    const float* Wq      = (const float*)d_in[3];
    const float* Wk      = (const float*)d_in[4];
    const float* Wv      = (const float*)d_in[5];
    const float* Wo      = (const float*)d_in[6];
    const float* scalars = (const float*)d_in[7];
    float* out = (float*)d_out;

    const size_t PL = (size_t)S_LEN * DMODEL;  // elements per 8 MB plane
    __bf16* p[12];
    for (int i = 0; i < 12; ++i) p[i] = (__bf16*)d_ws + i * PL;  // 96 MB total
    // p0..p3: input slot A (act hi/lo, wt hi/lo) — reused
    // p4..p7: input slot B (also later: p4 = vhT)
    // p8,p9: qh hi/lo (later attn-out hi/lo); p10,p11: kh hi/lo

    const float scale = 0.08838834764831844f;  // 1/sqrt(128)
    dim3 cg(2048 * 2048 / 4 / 256, 2), cb(256);
    dim3 gg(DMODEL / 128, S_LEN / 128, 1), gb(256);
    dim3 gg2(DMODEL / 128, S_LEN / 128, 2);

#define BH(x) (__hip_bfloat16*)(x)
    conv2<<<cg, cb, 0, stream>>>(query, BH(p[0]), BH(p[1]), 1.0f,
                                 Wq, BH(p[2]), BH(p[3]), scale);
    conv2<<<cg, cb, 0, stream>>>(key_, BH(p[4]), BH(p[5]), 1.0f,
                                 Wk, BH(p[6]), BH(p[7]), 1.0f);
    {
        GArgs gq = {p[0], p[1], p[2], p[3], nullptr, p[8], p[9]};
        GArgs gk = {p[4], p[5], p[6], p[7], nullptr, p[10], p[11]};
        gemm_nt3<2><<<gg2, gb, 0, stream>>>(gq, gk);
    }
    conv2<<<cg, cb, 0, stream>>>(Wv, BH(p[0]), BH(p[1]), 1.0f,
                                 value, BH(p[2]), BH(p[3]), 1.0f);
    {
        // vhT = (value @ Wv^T)^T = Wv @ value^T  (A = Wv, B = value)
        GArgs gv = {p[0], p[1], p[2], p[3], nullptr, p[4], nullptr};
        gemm_nt3<1><<<gg, gb, 0, stream>>>(gv, gv);
    }

    attn_mfma<<<dim3(S_LEN / 64, NHEAD), 256, 0, stream>>>(
        p[8], p[9], p[10], p[11], p[4], scalars, p[8], p[9]);

    conv2<<<dim3(2048 * 2048 / 4 / 256, 1), cb, 0, stream>>>(
        Wo, BH(p[0]), BH(p[1]), 1.0f, Wo, BH(p[0]), BH(p[1]), 1.0f);
    {
        GArgs go = {p[8], p[9], p[0], p[1], out, nullptr, nullptr};
        gemm_nt3<0><<<gg, gb, 0, stream>>>(go, go);
    }
#undef BH
}

// Round 9
// 521.888 us; speedup vs baseline: 1.2624x; 1.2624x over previous
//
#include <hip/hip_runtime.h>
#include <hip/hip_bf16.h>

// Problem: S=2048, D_MODEL=2048, H=16, HD=128
// out = softmax1((q@Wq^T)(k@Wk^T)^T / sqrt(HD)) @ (v@Wv^T) * scalars @ Wo^T
//
// Round 15:
//  - POST-MORTEM r14: r11+setprio+defer-max -> VGPR 112->212 (regalloc
//    blowup, likely setprio acting as a scheduling-region boundary hoisting
//    32 ds_read_b128 results). attn 276us. LESSON: micro-opts on this kernel
//    must be isolated one-at-a-time with VGPR checked before benching.
//  - attn_mfma: byte-exact r11 revert (verified 136.6us, 112 VGPR).
//  - conv4: the 4 conv launches fused to 2 (inputs are order-independent;
//    Wo converts into p6/p7 right after QK gemm frees them). 8->6 dispatches.
//  - gemm_nt3: unchanged from r10 (verified).

#define S_LEN 2048
#define DMODEL 2048
#define NHEAD 16
#define HEADD 128

typedef __bf16 bf16x8 __attribute__((ext_vector_type(8)));
typedef __bf16 bf16x4 __attribute__((ext_vector_type(4)));
typedef float f32x4 __attribute__((ext_vector_type(4)));

__device__ inline void async_copy16(const __bf16* g, __bf16* l) {
    __builtin_amdgcn_global_load_lds(
        (const __attribute__((address_space(1))) unsigned int*)g,
        (__attribute__((address_space(3))) unsigned int*)l, 16, 0, 0);
}

// ---- fp32 -> hi/lo bf16 split conversion, up to 4 matrices per launch ----
struct CArgs {
    const float* s[4];
    __hip_bfloat16* h[4];
    __hip_bfloat16* l[4];
    float sc[4];
};

__global__ __launch_bounds__(256) void conv4(CArgs a) {
    const int y = blockIdx.y;
    const float* s = a.s[y];
    __hip_bfloat16* ph = a.h[y];
    __hip_bfloat16* pl = a.l[y];
    const float sc = a.sc[y];
    size_t i4 = (size_t)blockIdx.x * 256 + threadIdx.x;  // float4 index
    float4 v = *(const float4*)&s[i4 * 4];
    float x0 = v.x * sc, x1 = v.y * sc, x2 = v.z * sc, x3 = v.w * sc;
    bf16x4 hv, lv;
    __bf16 a0 = (__bf16)x0, a1 = (__bf16)x1, a2 = (__bf16)x2, a3 = (__bf16)x3;
    hv[0] = a0; hv[1] = a1; hv[2] = a2; hv[3] = a3;
    lv[0] = (__bf16)(x0 - (float)a0); lv[1] = (__bf16)(x1 - (float)a1);
    lv[2] = (__bf16)(x2 - (float)a2); lv[3] = (__bf16)(x3 - (float)a3);
    *(bf16x4*)&ph[i4 * 4] = hv;
    *(bf16x4*)&pl[i4 * 4] = lv;
}

struct GArgs {
    const __bf16 *Ah, *Al, *Bh, *Bl;
    float* Cf;
    __bf16 *Ch, *Cl;
};

// ---- C = A @ B^T, pre-split hi/lo planes. Tile 128(M) x 128(N), BK=32.
// 256 threads = 4 waves in 2x2 grid; each wave owns a 64x64 sub-tile.
// Double-buffered LDS (64KB, 2 blocks/CU); one barrier per K-step.
// OUTMODE: 0 = fp32, 1 = bf16, 2 = hi/lo bf16 planes. blockIdx.z picks g0/g1.
template <int OUTMODE>
__global__ __launch_bounds__(256, 2) void gemm_nt3(GArgs g0, GArgs g1) {
    constexpr int K = DMODEL, N = DMODEL;
    const GArgs g = blockIdx.z ? g1 : g0;
    __shared__ __bf16 sAh[2][128 * 32], sAl[2][128 * 32];
    __shared__ __bf16 sBh[2][128 * 32], sBl[2][128 * 32];

    const int tid = threadIdx.x;   // 0..255
    const int lane = tid & 63;
    const int wave = tid >> 6;     // 0..3
    const int wr = wave >> 1;      // wave-row (2)
    const int wc = wave & 1;       // wave-col (2)
    const int qr = lane & 15;
    const int quad = lane >> 4;

    // XCD-bijective swizzle over the 16x16 2D grid (nwg=256, %8==0):
    // consecutive swz ids share the same XCD and the same A-panel row block.
    const int flat = blockIdx.y * gridDim.x + blockIdx.x;
    const int swz = (flat & 7) * 32 + (flat >> 3);
    const size_t row0 = (size_t)(swz >> 4) * 128;
    const size_t col0 = (size_t)(swz & 15) * 128;

    // staging: chunk (c*256+tid) -> LDS row = c*64 + (tid>>2), slot = tid&3;
    // slot holds global k-chunk (slot ^ (row&3)); read undoes with quad^(qr&3).
    const int srow = tid >> 2;
    const int k8 = (((tid & 3) ^ ((tid >> 2) & 3)) * 8);
    const __bf16* gAh = g.Ah + (row0 + srow) * K + k8;
    const __bf16* gAl = g.Al + (row0 + srow) * K + k8;
    const __bf16* gBh = g.Bh + (col0 + srow) * K + k8;
    const __bf16* gBl = g.Bl + (col0 + srow) * K + k8;

    f32x4 acc[4][4] = {};

    // issue 8 global_load_lds (32KB) for K-tile at column k0 into buffer b
    auto stage = [&](int b, int k0) {
#pragma unroll
        for (int c = 0; c < 2; ++c) {
            async_copy16(gAh + k0 + (size_t)c * 64 * K, &sAh[b][c * 2048 + tid * 8]);
            async_copy16(gAl + k0 + (size_t)c * 64 * K, &sAl[b][c * 2048 + tid * 8]);
            async_copy16(gBh + k0 + (size_t)c * 64 * K, &sBh[b][c * 2048 + tid * 8]);
            async_copy16(gBl + k0 + (size_t)c * 64 * K, &sBl[b][c * 2048 + tid * 8]);
        }
    };

    stage(0, 0);
    __syncthreads();  // prologue drain: buf0 ready

    const int aslot = (quad ^ (qr & 3)) * 8;
    int cur = 0;
    for (int k0 = 0; k0 < K; k0 += 32) {
        if (k0 + 32 < K) stage(cur ^ 1, k0 + 32);  // prefetch next tile

        bf16x8 a_h[4], a_l[4], b_h[4], b_l[4];
#pragma unroll
        for (int i = 0; i < 4; ++i) {
            a_h[i] = *(const bf16x8*)&sAh[cur][(wr * 64 + i * 16 + qr) * 32 + aslot];
            a_l[i] = *(const bf16x8*)&sAl[cur][(wr * 64 + i * 16 + qr) * 32 + aslot];
        }
#pragma unroll
        for (int j = 0; j < 4; ++j) {
            b_h[j] = *(const bf16x8*)&sBh[cur][(wc * 64 + j * 16 + qr) * 32 + aslot];
            b_l[j] = *(const bf16x8*)&sBl[cur][(wc * 64 + j * 16 + qr) * 32 + aslot];
        }
#pragma unroll
        for (int i = 0; i < 4; ++i)
#pragma unroll
            for (int j = 0; j < 4; ++j) {
                acc[i][j] = __builtin_amdgcn_mfma_f32_16x16x32_bf16(a_h[i], b_h[j], acc[i][j], 0, 0, 0);
                acc[i][j] = __builtin_amdgcn_mfma_f32_16x16x32_bf16(a_h[i], b_l[j], acc[i][j], 0, 0, 0);
                acc[i][j] = __builtin_amdgcn_mfma_f32_16x16x32_bf16(a_l[i], b_h[j], acc[i][j], 0, 0, 0);
            }
        __syncthreads();  // prefetch landed (vmcnt) + all reads of buf[cur] done
        cur ^= 1;
    }

    // epilogue: C/D layout col=lane&15, row=quad*4+reg
#pragma unroll
    for (int i = 0; i < 4; ++i)
#pragma unroll
        for (int j = 0; j < 4; ++j)
#pragma unroll
            for (int r = 0; r < 4; ++r) {
                size_t idx = (row0 + wr * 64 + i * 16 + quad * 4 + r) * N +
                             col0 + wc * 64 + j * 16 + qr;
                float x = acc[i][j][r];
                if (OUTMODE == 0) {
                    g.Cf[idx] = x;
                } else if (OUTMODE == 1) {
                    g.Ch[idx] = (__bf16)x;
                } else {
                    __bf16 hv = (__bf16)x;
                    g.Ch[idx] = hv;
                    g.Cl[idx] = (__bf16)(x - (float)hv);
                }
            }
}

// MFMA flash attention. Block = 64 q-rows x 1 head; 4 waves x 16 rows each.
// = r11 verified version (136.6us, 112 VGPR): VT in LDS, T14 reg prefetch,
// 2 barriers/tile, head-local XCD swizzle. NO setprio, NO defer-max, NO cap.
__global__ __launch_bounds__(256) void attn_mfma(const __bf16* __restrict__ qhi_g,
                                                 const __bf16* __restrict__ qlo_g,
                                                 const __bf16* __restrict__ khi_g,
                                                 const __bf16* __restrict__ klo_g,
                                                 const __bf16* __restrict__ vhT,
                                                 const float* __restrict__ scalars,
                                                 __bf16* __restrict__ ohi_g,
                                                 __bf16* __restrict__ olo_g) {
    // head-locality XCD swizzle: XCD x (= flat%8 dispatch round-robin) owns
    // heads {2x, 2x+1}; K/V working set per XCD = 2.5MB < 4MB L2. Bijective.
    const int flatb = blockIdx.y * gridDim.x + blockIdx.x;  // 0..511
    const int ib = flatb >> 3;                              // 0..63
    const int h = (flatb & 7) * 2 + (ib >> 5);
    const int q0 = (ib & 31) * 64;

    __shared__ __align__(16) __bf16 Khi[64][136];  // padded: 272B stride
    __shared__ __align__(16) __bf16 Klo[64][136];
    __shared__ __align__(16) __bf16 VT[128][72];   // [head-dim][kpos], 144B stride
    __shared__ __align__(16) __bf16 Ps[64][72];    // [q-row][kpos] (wave-private rows)

    const int tid = threadIdx.x;
    const int lane = tid & 63;
    const int wave = tid >> 6;
    const int qr = lane & 15;
    const int quad = lane >> 4;

    // per-thread staging coordinates (fixed across tiles)
    const int kp0 = tid >> 4;           // K row base (+16 per chunk), 0..15
    const int kc8 = (tid & 15) * 8;     // K col byte-slot
    const int dm0 = tid >> 3;           // V row base (+32 per chunk), 0..31
    const int vc8 = (tid & 7) * 8;      // V col slot
    const __bf16* gK_hi = khi_g + (size_t)kp0 * DMODEL + h * HEADD + kc8;
    const __bf16* gK_lo = klo_g + (size_t)kp0 * DMODEL + h * HEADD + kc8;
    const __bf16* gVT = vhT + (size_t)(h * HEADD + dm0) * S_LEN + vc8;

    bf16x8 qfh[4], qfl[4];
    {
        const __bf16* qrh = qhi_g + (size_t)(q0 + wave * 16 + qr) * DMODEL + h * HEADD;
        const __bf16* qrl = qlo_g + (size_t)(q0 + wave * 16 + qr) * DMODEL + h * HEADD;
#pragma unroll
        for (int kc = 0; kc < 4; ++kc) {
            qfh[kc] = *(const bf16x8*)&qrh[kc * 32 + quad * 8];
            qfl[kc] = *(const bf16x8*)&qrl[kc * 32 + quad * 8];
        }
    }

    // register-staged K/V tile (T14 async split): 12 x 16B per thread
    bf16x8 rKh[4], rKl[4], rV[4];
    auto load_regs = [&](int k0) {
#pragma unroll
        for (int i = 0; i < 4; ++i) {
            size_t go = (size_t)(k0 + i * 16) * DMODEL;
            rKh[i] = *(const bf16x8*)&gK_hi[go];
            rKl[i] = *(const bf16x8*)&gK_lo[go];
            rV[i] = *(const bf16x8*)&gVT[(size_t)(i * 32) * S_LEN + k0];
        }
    };
    auto write_lds = [&]() {
#pragma unroll
        for (int i = 0; i < 4; ++i) {
            *(bf16x8*)&Khi[kp0 + i * 16][kc8] = rKh[i];
            *(bf16x8*)&Klo[kp0 + i * 16][kc8] = rKl[i];
            *(bf16x8*)&VT[dm0 + i * 32][vc8] = rV[i];
        }
    };

    f32x4 oacc[8] = {};
    float m_r[4], l_r[4];
#pragma unroll
    for (int r = 0; r < 4; ++r) { m_r[r] = 0.f; l_r[r] = 1.f; }  // softmax1 init

    load_regs(0);
    for (int k0 = 0; k0 < S_LEN; k0 += 64) {
        write_lds();          // lgkmcnt ordering by compiler
        __syncthreads();      // tile k0 visible to all waves
        if (k0 + 64 < S_LEN) load_regs(k0 + 64);  // flies under compute

        f32x4 S[4] = {};
#pragma unroll
        for (int jt = 0; jt < 4; ++jt) {
#pragma unroll
            for (int kc = 0; kc < 4; ++kc) {
                bf16x8 kh8 = *(const bf16x8*)&Khi[jt * 16 + qr][kc * 32 + quad * 8];
                bf16x8 kl8 = *(const bf16x8*)&Klo[jt * 16 + qr][kc * 32 + quad * 8];
                S[jt] = __builtin_amdgcn_mfma_f32_16x16x32_bf16(qfh[kc], kh8, S[jt], 0, 0, 0);
                S[jt] = __builtin_amdgcn_mfma_f32_16x16x32_bf16(qfh[kc], kl8, S[jt], 0, 0, 0);
                S[jt] = __builtin_amdgcn_mfma_f32_16x16x32_bf16(qfl[kc], kh8, S[jt], 0, 0, 0);
            }
        }

#pragma unroll
        for (int r = 0; r < 4; ++r) {
            float mx = fmaxf(fmaxf(S[0][r], S[1][r]), fmaxf(S[2][r], S[3][r]));
#pragma unroll
            for (int m = 1; m < 16; m <<= 1) mx = fmaxf(mx, __shfl_xor(mx, m, 64));
            float m_new = fmaxf(m_r[r], mx);
            float alpha = __expf(m_r[r] - m_new);
            float sum = 0.f;
            int prow = wave * 16 + quad * 4 + r;
#pragma unroll
            for (int jt = 0; jt < 4; ++jt) {
                float e = __expf(S[jt][r] - m_new);
                sum += e;
                Ps[prow][jt * 16 + qr] = (__bf16)e;
            }
#pragma unroll
            for (int m = 1; m < 16; m <<= 1) sum += __shfl_xor(sum, m, 64);
            l_r[r] = l_r[r] * alpha + sum;
            m_r[r] = m_new;
#pragma unroll
            for (int nt = 0; nt < 8; ++nt) oacc[nt][r] *= alpha;
        }
        // NO barrier: Ps rows [wave*16, wave*16+16) are wave-private.

#pragma unroll
        for (int kc = 0; kc < 2; ++kc) {
            bf16x8 pf = *(const bf16x8*)&Ps[wave * 16 + qr][kc * 32 + quad * 8];
#pragma unroll
            for (int nt = 0; nt < 8; ++nt) {
                bf16x8 vf = *(const bf16x8*)&VT[nt * 16 + qr][kc * 32 + quad * 8];
                oacc[nt] = __builtin_amdgcn_mfma_f32_16x16x32_bf16(pf, vf, oacc[nt], 0, 0, 0);
            }
        }
        __syncthreads();  // all waves done reading K/VT before next write_lds
    }

    const float sh = scalars[h];
#pragma unroll
    for (int r = 0; r < 4; ++r) {
        float wm = sh / l_r[r];
        size_t rowoff = (size_t)(q0 + wave * 16 + quad * 4 + r) * DMODEL + h * HEADD;
#pragma unroll
        for (int nt = 0; nt < 8; ++nt) {
            float x = oacc[nt][r] * wm;
            __bf16 hv = (__bf16)x;
            ohi_g[rowoff + nt * 16 + qr] = hv;
            olo_g[rowoff + nt * 16 + qr] = (__bf16)(x - (float)hv);
        }
    }
}

extern "C" void kernel_launch(void* const* d_in, const int* in_sizes, int n_in,
                              void* d_out, int out_size, void* d_ws, size_t ws_size,
                              hipStream_t stream) {
    const float* query   = (const float*)d_in[0];
    const float* key_    = (const float*)d_in[1];
    const float* value   = (const float*)d_in[2];
    const float* Wq      = (const float*)d_in[3];
    const float* Wk      = (const float*)d_in[4];
    const float* Wv      = (const float*)d_in[5];
    const float* Wo      = (const float*)d_in[6];
    const float* scalars = (const float*)d_in[7];
    float* out = (float*)d_out;

    const size_t PL = (size_t)S_LEN * DMODEL;  // elements per 8 MB plane
    __bf16* p[12];
    for (int i = 0; i < 12; ++i) p[i] = (__bf16*)d_ws + i * PL;  // 96 MB total
    // p0,p1: q hi/lo -> later Wv hi/lo
    // p2,p3: Wq hi/lo -> later value hi/lo
    // p4,p5: k hi/lo -> p4 later vhT
    // p6,p7: Wk hi/lo -> later Wo hi/lo (free after QK gemm)
    // p8,p9: qh hi/lo -> attn-out hi/lo; p10,p11: kh hi/lo

    const float scale = 0.08838834764831844f;  // 1/sqrt(128)
    dim3 gg(DMODEL / 128, S_LEN / 128, 1), gb(256);
    dim3 gg2(DMODEL / 128, S_LEN / 128, 2);

#define BH(x) (__hip_bfloat16*)(x)
    {   // fused input conversion #1: query, Wq (scale folded), key, Wk
        CArgs ca;
        ca.s[0] = query; ca.s[1] = Wq; ca.s[2] = key_; ca.s[3] = Wk;
        ca.h[0] = BH(p[0]); ca.l[0] = BH(p[1]);
        ca.h[1] = BH(p[2]); ca.l[1] = BH(p[3]);
        ca.h[2] = BH(p[4]); ca.l[2] = BH(p[5]);
        ca.h[3] = BH(p[6]); ca.l[3] = BH(p[7]);
        ca.sc[0] = 1.0f; ca.sc[1] = scale; ca.sc[2] = 1.0f; ca.sc[3] = 1.0f;
        conv4<<<dim3(2048 * 2048 / 4 / 256, 4), 256, 0, stream>>>(ca);
    }
    {   // fused Q/K projections
        GArgs gq = {p[0], p[1], p[2], p[3], nullptr, p[8], p[9]};
        GArgs gk = {p[4], p[5], p[6], p[7], nullptr, p[10], p[11]};
        gemm_nt3<2><<<gg2, gb, 0, stream>>>(gq, gk);
    }
    {   // fused input conversion #2: Wv, value, Wo (into p6/p7, freed by QK)
        CArgs cc;
        cc.s[0] = Wv; cc.s[1] = value; cc.s[2] = Wo; cc.s[3] = Wo;
        cc.h[0] = BH(p[0]); cc.l[0] = BH(p[1]);
        cc.h[1] = BH(p[2]); cc.l[1] = BH(p[3]);
        cc.h[2] = BH(p[6]); cc.l[2] = BH(p[7]);
        cc.h[3] = BH(p[6]); cc.l[3] = BH(p[7]);
        cc.sc[0] = 1.0f; cc.sc[1] = 1.0f; cc.sc[2] = 1.0f; cc.sc[3] = 1.0f;
        conv4<<<dim3(2048 * 2048 / 4 / 256, 3), 256, 0, stream>>>(cc);
    }
    {   // vhT = (value @ Wv^T)^T = Wv @ value^T  (A = Wv, B = value)
        GArgs gv = {p[0], p[1], p[2], p[3], nullptr, p[4], nullptr};
        gemm_nt3<1><<<gg, gb, 0, stream>>>(gv, gv);
    }

    attn_mfma<<<dim3(S_LEN / 64, NHEAD), 256, 0, stream>>>(
        p[8], p[9], p[10], p[11], p[4], scalars, p[8], p[9]);

    {   // out = attn_out @ Wo^T
        GArgs go = {p[8], p[9], p[6], p[7], out, nullptr, nullptr};
        gemm_nt3<0><<<gg, gb, 0, stream>>>(go, go);
    }
#undef BH
}

// Round 10
// 512.589 us; speedup vs baseline: 1.2853x; 1.0181x over previous
//
#include <hip/hip_runtime.h>
#include <hip/hip_bf16.h>

// Problem: S=2048, D_MODEL=2048, H=16, HD=128
// out = softmax1((q@Wq^T)(k@Wk^T)^T / sqrt(HD)) @ (v@Wv^T) * scalars @ Wo^T
//
// Round 16:
//  - POST-MORTEM r15: revert+fusion worked (522us best; attn 131us).
//  - attn_mfma v6: QBLK=128 / 8 waves / 512 thr (r13's indexing, which
//    PASSED correctness; its perf fail was solely launch_bounds(512,4)
//    forcing VGPR=64 + spills). Plain launch_bounds(512). Double-buffered
//    K/V LDS (123KB, 1 block/CU -> VGPR up to 256 is occupancy-free):
//    1 barrier/tile (was 2), write_lds overlaps compute, K/V staged once
//    per CU per tile (was 2x redundant across the 2 cohabiting blocks).
//  - conv4 / gemm_nt3: unchanged from r15 (verified).

#define S_LEN 2048
#define DMODEL 2048
#define NHEAD 16
#define HEADD 128

typedef __bf16 bf16x8 __attribute__((ext_vector_type(8)));
typedef __bf16 bf16x4 __attribute__((ext_vector_type(4)));
typedef float f32x4 __attribute__((ext_vector_type(4)));

__device__ inline void async_copy16(const __bf16* g, __bf16* l) {
    __builtin_amdgcn_global_load_lds(
        (const __attribute__((address_space(1))) unsigned int*)g,
        (__attribute__((address_space(3))) unsigned int*)l, 16, 0, 0);
}

// ---- fp32 -> hi/lo bf16 split conversion, up to 4 matrices per launch ----
struct CArgs {
    const float* s[4];
    __hip_bfloat16* h[4];
    __hip_bfloat16* l[4];
    float sc[4];
};

__global__ __launch_bounds__(256) void conv4(CArgs a) {
    const int y = blockIdx.y;
    const float* s = a.s[y];
    __hip_bfloat16* ph = a.h[y];
    __hip_bfloat16* pl = a.l[y];
    const float sc = a.sc[y];
    size_t i4 = (size_t)blockIdx.x * 256 + threadIdx.x;  // float4 index
    float4 v = *(const float4*)&s[i4 * 4];
    float x0 = v.x * sc, x1 = v.y * sc, x2 = v.z * sc, x3 = v.w * sc;
    bf16x4 hv, lv;
    __bf16 a0 = (__bf16)x0, a1 = (__bf16)x1, a2 = (__bf16)x2, a3 = (__bf16)x3;
    hv[0] = a0; hv[1] = a1; hv[2] = a2; hv[3] = a3;
    lv[0] = (__bf16)(x0 - (float)a0); lv[1] = (__bf16)(x1 - (float)a1);
    lv[2] = (__bf16)(x2 - (float)a2); lv[3] = (__bf16)(x3 - (float)a3);
    *(bf16x4*)&ph[i4 * 4] = hv;
    *(bf16x4*)&pl[i4 * 4] = lv;
}

struct GArgs {
    const __bf16 *Ah, *Al, *Bh, *Bl;
    float* Cf;
    __bf16 *Ch, *Cl;
};

// ---- C = A @ B^T, pre-split hi/lo planes. Tile 128(M) x 128(N), BK=32.
// 256 threads = 4 waves in 2x2 grid; each wave owns a 64x64 sub-tile.
// Double-buffered LDS (64KB, 2 blocks/CU); one barrier per K-step.
// OUTMODE: 0 = fp32, 1 = bf16, 2 = hi/lo bf16 planes. blockIdx.z picks g0/g1.
template <int OUTMODE>
__global__ __launch_bounds__(256, 2) void gemm_nt3(GArgs g0, GArgs g1) {
    constexpr int K = DMODEL, N = DMODEL;
    const GArgs g = blockIdx.z ? g1 : g0;
    __shared__ __bf16 sAh[2][128 * 32], sAl[2][128 * 32];
    __shared__ __bf16 sBh[2][128 * 32], sBl[2][128 * 32];

    const int tid = threadIdx.x;   // 0..255
    const int lane = tid & 63;
    const int wave = tid >> 6;     // 0..3
    const int wr = wave >> 1;      // wave-row (2)
    const int wc = wave & 1;       // wave-col (2)
    const int qr = lane & 15;
    const int quad = lane >> 4;

    // XCD-bijective swizzle over the 16x16 2D grid (nwg=256, %8==0):
    // consecutive swz ids share the same XCD and the same A-panel row block.
    const int flat = blockIdx.y * gridDim.x + blockIdx.x;
    const int swz = (flat & 7) * 32 + (flat >> 3);
    const size_t row0 = (size_t)(swz >> 4) * 128;
    const size_t col0 = (size_t)(swz & 15) * 128;

    // staging: chunk (c*256+tid) -> LDS row = c*64 + (tid>>2), slot = tid&3;
    // slot holds global k-chunk (slot ^ (row&3)); read undoes with quad^(qr&3).
    const int srow = tid >> 2;
    const int k8 = (((tid & 3) ^ ((tid >> 2) & 3)) * 8);
    const __bf16* gAh = g.Ah + (row0 + srow) * K + k8;
    const __bf16* gAl = g.Al + (row0 + srow) * K + k8;
    const __bf16* gBh = g.Bh + (col0 + srow) * K + k8;
    const __bf16* gBl = g.Bl + (col0 + srow) * K + k8;

    f32x4 acc[4][4] = {};

    // issue 8 global_load_lds (32KB) for K-tile at column k0 into buffer b
    auto stage = [&](int b, int k0) {
#pragma unroll
        for (int c = 0; c < 2; ++c) {
            async_copy16(gAh + k0 + (size_t)c * 64 * K, &sAh[b][c * 2048 + tid * 8]);
            async_copy16(gAl + k0 + (size_t)c * 64 * K, &sAl[b][c * 2048 + tid * 8]);
            async_copy16(gBh + k0 + (size_t)c * 64 * K, &sBh[b][c * 2048 + tid * 8]);
            async_copy16(gBl + k0 + (size_t)c * 64 * K, &sBl[b][c * 2048 + tid * 8]);
        }
    };

    stage(0, 0);
    __syncthreads();  // prologue drain: buf0 ready

    const int aslot = (quad ^ (qr & 3)) * 8;
    int cur = 0;
    for (int k0 = 0; k0 < K; k0 += 32) {
        if (k0 + 32 < K) stage(cur ^ 1, k0 + 32);  // prefetch next tile

        bf16x8 a_h[4], a_l[4], b_h[4], b_l[4];
#pragma unroll
        for (int i = 0; i < 4; ++i) {
            a_h[i] = *(const bf16x8*)&sAh[cur][(wr * 64 + i * 16 + qr) * 32 + aslot];
            a_l[i] = *(const bf16x8*)&sAl[cur][(wr * 64 + i * 16 + qr) * 32 + aslot];
        }
#pragma unroll
        for (int j = 0; j < 4; ++j) {
            b_h[j] = *(const bf16x8*)&sBh[cur][(wc * 64 + j * 16 + qr) * 32 + aslot];
            b_l[j] = *(const bf16x8*)&sBl[cur][(wc * 64 + j * 16 + qr) * 32 + aslot];
        }
#pragma unroll
        for (int i = 0; i < 4; ++i)
#pragma unroll
            for (int j = 0; j < 4; ++j) {
                acc[i][j] = __builtin_amdgcn_mfma_f32_16x16x32_bf16(a_h[i], b_h[j], acc[i][j], 0, 0, 0);
                acc[i][j] = __builtin_amdgcn_mfma_f32_16x16x32_bf16(a_h[i], b_l[j], acc[i][j], 0, 0, 0);
                acc[i][j] = __builtin_amdgcn_mfma_f32_16x16x32_bf16(a_l[i], b_h[j], acc[i][j], 0, 0, 0);
            }
        __syncthreads();  // prefetch landed (vmcnt) + all reads of buf[cur] done
        cur ^= 1;
    }

    // epilogue: C/D layout col=lane&15, row=quad*4+reg
#pragma unroll
    for (int i = 0; i < 4; ++i)
#pragma unroll
        for (int j = 0; j < 4; ++j)
#pragma unroll
            for (int r = 0; r < 4; ++r) {
                size_t idx = (row0 + wr * 64 + i * 16 + quad * 4 + r) * N +
                             col0 + wc * 64 + j * 16 + qr;
                float x = acc[i][j][r];
                if (OUTMODE == 0) {
                    g.Cf[idx] = x;
                } else if (OUTMODE == 1) {
                    g.Ch[idx] = (__bf16)x;
                } else {
                    __bf16 hv = (__bf16)x;
                    g.Ch[idx] = hv;
                    g.Cl[idx] = (__bf16)(x - (float)hv);
                }
            }
}

// MFMA flash attention. Block = 128 q-rows x 1 head; 8 waves x 16 rows each.
// v6: QBLK=128 (r13 indexing, correctness-verified), plain launch_bounds(512),
// double-buffered K/V LDS (123KB, 1 block/CU), 1 barrier/tile, T14 prefetch.
__global__ __launch_bounds__(512) void attn_mfma(const __bf16* __restrict__ qhi_g,
                                                 const __bf16* __restrict__ qlo_g,
                                                 const __bf16* __restrict__ khi_g,
                                                 const __bf16* __restrict__ klo_g,
                                                 const __bf16* __restrict__ vhT,
                                                 const float* __restrict__ scalars,
                                                 __bf16* __restrict__ ohi_g,
                                                 __bf16* __restrict__ olo_g) {
    // head-locality XCD swizzle: XCD x (= flatb%8 dispatch round-robin) owns
    // heads {2x, 2x+1}; K/V working set per XCD = 2.5MB < 4MB L2. Bijective:
    // flatb in [0,256): h = (flatb&7)*2 + (ib>>4), q0 = (ib&15)*128, ib=flatb>>3.
    const int flatb = blockIdx.y * gridDim.x + blockIdx.x;  // 0..255
    const int ib = flatb >> 3;                              // 0..31
    const int h = (flatb & 7) * 2 + (ib >> 4);
    const int q0 = (ib & 15) * 128;

    __shared__ __align__(16) __bf16 Khi[2][64][136];  // padded: 272B stride
    __shared__ __align__(16) __bf16 Klo[2][64][136];
    __shared__ __align__(16) __bf16 VT[2][128][72];   // [head-dim][kpos]
    __shared__ __align__(16) __bf16 Ps[128][72];      // [q-row][kpos] wave-private rows

    const int tid = threadIdx.x;   // 0..511
    const int lane = tid & 63;
    const int wave = tid >> 6;     // 0..7
    const int qr = lane & 15;
    const int quad = lane >> 4;

    // per-thread staging coordinates (fixed across tiles), 512-thread layout
    const int kp0 = tid >> 4;           // 0..31; K rows kp0, kp0+32
    const int kc8 = (tid & 15) * 8;     // K col byte-slot (128 cols)
    const int dm0 = tid >> 3;           // 0..63; V rows dm0, dm0+64
    const int vc8 = (tid & 7) * 8;      // V col slot (64 cols)
    const __bf16* gK_hi = khi_g + (size_t)kp0 * DMODEL + h * HEADD + kc8;
    const __bf16* gK_lo = klo_g + (size_t)kp0 * DMODEL + h * HEADD + kc8;
    const __bf16* gVT = vhT + (size_t)(h * HEADD + dm0) * S_LEN + vc8;

    bf16x8 qfh[4], qfl[4];
    {
        const __bf16* qrh = qhi_g + (size_t)(q0 + wave * 16 + qr) * DMODEL + h * HEADD;
        const __bf16* qrl = qlo_g + (size_t)(q0 + wave * 16 + qr) * DMODEL + h * HEADD;
#pragma unroll
        for (int kc = 0; kc < 4; ++kc) {
            qfh[kc] = *(const bf16x8*)&qrh[kc * 32 + quad * 8];
            qfl[kc] = *(const bf16x8*)&qrl[kc * 32 + quad * 8];
        }
    }

    // register-staged K/V tile (T14 async split): 6 x 16B per thread
    bf16x8 rKh[2], rKl[2], rV[2];
    auto load_regs = [&](int k0) {
#pragma unroll
        for (int i = 0; i < 2; ++i) {
            size_t go = (size_t)(k0 + i * 32) * DMODEL;
            rKh[i] = *(const bf16x8*)&gK_hi[go];
            rKl[i] = *(const bf16x8*)&gK_lo[go];
            rV[i] = *(const bf16x8*)&gVT[(size_t)(i * 64) * S_LEN + k0];
        }
    };
    auto write_lds = [&](int b) {
#pragma unroll
        for (int i = 0; i < 2; ++i) {
            *(bf16x8*)&Khi[b][kp0 + i * 32][kc8] = rKh[i];
            *(bf16x8*)&Klo[b][kp0 + i * 32][kc8] = rKl[i];
            *(bf16x8*)&VT[b][dm0 + i * 64][vc8] = rV[i];
        }
    };

    f32x4 oacc[8] = {};
    float m_r[4], l_r[4];
#pragma unroll
    for (int r = 0; r < 4; ++r) { m_r[r] = 0.f; l_r[r] = 1.f; }  // softmax1 init

    load_regs(0);
    write_lds(0);
    int cur = 0;
    for (int k0 = 0; k0 < S_LEN; k0 += 64) {
        __syncthreads();  // buf[cur] writes visible; prior reads of cur^1 done
        if (k0 + 64 < S_LEN) load_regs(k0 + 64);  // next tile -> regs (async)

        f32x4 S[4] = {};
#pragma unroll
        for (int jt = 0; jt < 4; ++jt) {
#pragma unroll
            for (int kc = 0; kc < 4; ++kc) {
                bf16x8 kh8 = *(const bf16x8*)&Khi[cur][jt * 16 + qr][kc * 32 + quad * 8];
                bf16x8 kl8 = *(const bf16x8*)&Klo[cur][jt * 16 + qr][kc * 32 + quad * 8];
                S[jt] = __builtin_amdgcn_mfma_f32_16x16x32_bf16(qfh[kc], kh8, S[jt], 0, 0, 0);
                S[jt] = __builtin_amdgcn_mfma_f32_16x16x32_bf16(qfh[kc], kl8, S[jt], 0, 0, 0);
                S[jt] = __builtin_amdgcn_mfma_f32_16x16x32_bf16(qfl[kc], kh8, S[jt], 0, 0, 0);
            }
        }

#pragma unroll
        for (int r = 0; r < 4; ++r) {
            float mx = fmaxf(fmaxf(S[0][r], S[1][r]), fmaxf(S[2][r], S[3][r]));
#pragma unroll
            for (int m = 1; m < 16; m <<= 1) mx = fmaxf(mx, __shfl_xor(mx, m, 64));
            float m_new = fmaxf(m_r[r], mx);
            float alpha = __expf(m_r[r] - m_new);
            float sum = 0.f;
            int prow = wave * 16 + quad * 4 + r;
#pragma unroll
            for (int jt = 0; jt < 4; ++jt) {
                float e = __expf(S[jt][r] - m_new);
                sum += e;
                Ps[prow][jt * 16 + qr] = (__bf16)e;
            }
#pragma unroll
            for (int m = 1; m < 16; m <<= 1) sum += __shfl_xor(sum, m, 64);
            l_r[r] = l_r[r] * alpha + sum;
            m_r[r] = m_new;
#pragma unroll
            for (int nt = 0; nt < 8; ++nt) oacc[nt][r] *= alpha;
        }
        // NO barrier: Ps rows [wave*16, wave*16+16) are wave-private.

#pragma unroll
        for (int kc = 0; kc < 2; ++kc) {
            bf16x8 pf = *(const bf16x8*)&Ps[wave * 16 + qr][kc * 32 + quad * 8];
#pragma unroll
            for (int nt = 0; nt < 8; ++nt) {
                bf16x8 vf = *(const bf16x8*)&VT[cur][nt * 16 + qr][kc * 32 + quad * 8];
                oacc[nt] = __builtin_amdgcn_mfma_f32_16x16x32_bf16(pf, vf, oacc[nt], 0, 0, 0);
            }
        }

        if (k0 + 64 < S_LEN) write_lds(cur ^ 1);  // other buffer: no race with
        cur ^= 1;                                 // this tile's readers
    }

    const float sh = scalars[h];
#pragma unroll
    for (int r = 0; r < 4; ++r) {
        float wm = sh / l_r[r];
        size_t rowoff = (size_t)(q0 + wave * 16 + quad * 4 + r) * DMODEL + h * HEADD;
#pragma unroll
        for (int nt = 0; nt < 8; ++nt) {
            float x = oacc[nt][r] * wm;
            __bf16 hv = (__bf16)x;
            ohi_g[rowoff + nt * 16 + qr] = hv;
            olo_g[rowoff + nt * 16 + qr] = (__bf16)(x - (float)hv);
        }
    }
}

extern "C" void kernel_launch(void* const* d_in, const int* in_sizes, int n_in,
                              void* d_out, int out_size, void* d_ws, size_t ws_size,
                              hipStream_t stream) {
    const float* query   = (const float*)d_in[0];
    const float* key_    = (const float*)d_in[1];
    const float* value   = (const float*)d_in[2];
    const float* Wq      = (const float*)d_in[3];
    const float* Wk      = (const float*)d_in[4];
    const float* Wv      = (const float*)d_in[5];
    const float* Wo      = (const float*)d_in[6];
    const float* scalars = (const float*)d_in[7];
    float* out = (float*)d_out;

    const size_t PL = (size_t)S_LEN * DMODEL;  // elements per 8 MB plane
    __bf16* p[12];
    for (int i = 0; i < 12; ++i) p[i] = (__bf16*)d_ws + i * PL;  // 96 MB total
    // p0,p1: q hi/lo -> later Wv hi/lo
    // p2,p3: Wq hi/lo -> later value hi/lo
    // p4,p5: k hi/lo -> p4 later vhT
    // p6,p7: Wk hi/lo -> later Wo hi/lo (free after QK gemm)
    // p8,p9: qh hi/lo -> attn-out hi/lo; p10,p11: kh hi/lo

    const float scale = 0.08838834764831844f;  // 1/sqrt(128)
    dim3 gg(DMODEL / 128, S_LEN / 128, 1), gb(256);
    dim3 gg2(DMODEL / 128, S_LEN / 128, 2);

#define BH(x) (__hip_bfloat16*)(x)
    {   // fused input conversion #1: query, Wq (scale folded), key, Wk
        CArgs ca;
        ca.s[0] = query; ca.s[1] = Wq; ca.s[2] = key_; ca.s[3] = Wk;
        ca.h[0] = BH(p[0]); ca.l[0] = BH(p[1]);
        ca.h[1] = BH(p[2]); ca.l[1] = BH(p[3]);
        ca.h[2] = BH(p[4]); ca.l[2] = BH(p[5]);
        ca.h[3] = BH(p[6]); ca.l[3] = BH(p[7]);
        ca.sc[0] = 1.0f; ca.sc[1] = scale; ca.sc[2] = 1.0f; ca.sc[3] = 1.0f;
        conv4<<<dim3(2048 * 2048 / 4 / 256, 4), 256, 0, stream>>>(ca);
    }
    {   // fused Q/K projections
        GArgs gq = {p[0], p[1], p[2], p[3], nullptr, p[8], p[9]};
        GArgs gk = {p[4], p[5], p[6], p[7], nullptr, p[10], p[11]};
        gemm_nt3<2><<<gg2, gb, 0, stream>>>(gq, gk);
    }
    {   // fused input conversion #2: Wv, value, Wo (into p6/p7, freed by QK)
        CArgs cc;
        cc.s[0] = Wv; cc.s[1] = value; cc.s[2] = Wo; cc.s[3] = Wo;
        cc.h[0] = BH(p[0]); cc.l[0] = BH(p[1]);
        cc.h[1] = BH(p[2]); cc.l[1] = BH(p[3]);
        cc.h[2] = BH(p[6]); cc.l[2] = BH(p[7]);
        cc.h[3] = BH(p[6]); cc.l[3] = BH(p[7]);
        cc.sc[0] = 1.0f; cc.sc[1] = 1.0f; cc.sc[2] = 1.0f; cc.sc[3] = 1.0f;
        conv4<<<dim3(2048 * 2048 / 4 / 256, 3), 256, 0, stream>>>(cc);
    }
    {   // vhT = (value @ Wv^T)^T = Wv @ value^T  (A = Wv, B = value)
        GArgs gv = {p[0], p[1], p[2], p[3], nullptr, p[4], nullptr};
        gemm_nt3<1><<<gg, gb, 0, stream>>>(gv, gv);
    }

    attn_mfma<<<dim3(S_LEN / 128, NHEAD), 512, 0, stream>>>(
        p[8], p[9], p[10], p[11], p[4], scalars, p[8], p[9]);

    {   // out = attn_out @ Wo^T
        GArgs go = {p[8], p[9], p[6], p[7], out, nullptr, nullptr};
        gemm_nt3<0><<<gg, gb, 0, stream>>>(go, go);
    }
#undef BH
}